// Round 21
// baseline (113.700 us; speedup 1.0000x reference)
//
#include <hip/hip_runtime.h>

// Transformer layer, MI355X/gfx950.
// B=2, N=2048, C=512, H=8, D=64. Softmax over HEAD axis (faithful to ref).
// Attention v8.2 (~45us, frozen). GEMMs: 2-phase dbuf + XOR-swizzled LDS
// (BK=64 qkv/fc1; BK=128 proj/fc2). qkv epilogue writes V transposed to vt.
// NEW: proj fuses the 4-partial combine into its A reg-staging (cmb4 kernel
// + attnb round-trip deleted).

typedef unsigned short u16;
typedef unsigned int u32;
typedef __attribute__((ext_vector_type(4))) float f32x4;
typedef __attribute__((ext_vector_type(4))) u32 u32x4;
typedef __attribute__((ext_vector_type(2))) u32 u32x2;
typedef __attribute__((ext_vector_type(8))) short sv8;
typedef __attribute__((ext_vector_type(8))) __bf16 bfv8;
typedef __attribute__((ext_vector_type(8))) u16 usv8;
typedef __attribute__((ext_vector_type(4))) u16 usv4;

#define DEV static __device__ __forceinline__

DEV u16 f2bf(float f) {  // RNE fp32 -> bf16
  u32 x = __builtin_bit_cast(u32, f);
  return (u16)((x + 0x7fffu + ((x >> 16) & 1u)) >> 16);
}

DEV float bf2f(u16 v) { return __builtin_bit_cast(float, (u32)v << 16); }

DEV f32x4 mfma16(sv8 a, sv8 b, f32x4 c) {
  return __builtin_amdgcn_mfma_f32_16x16x32_bf16(
      __builtin_bit_cast(bfv8, a), __builtin_bit_cast(bfv8, b), c, 0, 0, 0);
}

DEV void gload_lds16(const void* g, void* l) {
  __builtin_amdgcn_global_load_lds(
      (const __attribute__((address_space(1))) u32*)g,
      (__attribute__((address_space(3))) u32*)l, 16, 0, 0);
}

DEV u32 pkbf(float a, float b) {
  u32 r;
  asm("v_cvt_pk_bf16_f32 %0, %1, %2" : "=v"(r) : "v"(a), "v"(b));
  return r;
}

DEV float gelu_f(float t) {
  // tanh-form GELU: 0.5t(1+tanh(0.79788456(t+0.044715t^3))); |err| < 3e-3
  const float u = t * (0.7978845608028654f + 0.03567740814183556f * t * t);
  const float e = __builtin_amdgcn_exp2f(u * 2.8853900817779268f);  // e^(2u)
  const float th = 1.0f - 2.0f * __builtin_amdgcn_rcpf(e + 1.0f);
  return 0.5f * t * (1.0f + th);
}

// ---------------- prep: weight cast (blocks 0..3071) + LN1 (3072..4095) ----
__global__ __launch_bounds__(256) void prep_kernel(
    const float* __restrict__ s0, const float* __restrict__ s1,
    const float* __restrict__ s2, const float* __restrict__ s3,
    u16* __restrict__ d0, u16* __restrict__ d1,
    u16* __restrict__ d2, u16* __restrict__ d3,
    const float* __restrict__ x, const float* __restrict__ g,
    const float* __restrict__ bb, u16* __restrict__ out)
{
  if (blockIdx.x < 3072) {
    int i = blockIdx.x * 256 + threadIdx.x;  // vec4 index, 786432 total
    const float* s; u16* d; int off;
    if (i < 196608)      { s = s0; d = d0; off = i; }
    else if (i < 262144) { s = s1; d = d1; off = i - 196608; }
    else if (i < 524288) { s = s2; d = d2; off = i - 262144; }
    else                 { s = s3; d = d3; off = i - 524288; }
    float4 v = ((const float4*)s)[off];
    usv4 r; r.x = f2bf(v.x); r.y = f2bf(v.y); r.z = f2bf(v.z); r.w = f2bf(v.w);
    *(usv4*)(d + (size_t)off * 4) = r;
    return;
  }
  const int row = ((blockIdx.x - 3072) << 2) + (threadIdx.x >> 6);
  const int lane = threadIdx.x & 63;
  const float4* xr = (const float4*)(x + ((size_t)row << 9));
  float4 a = xr[lane * 2], c = xr[lane * 2 + 1];
  float s  = a.x + a.y + a.z + a.w + c.x + c.y + c.z + c.w;
  float ss = a.x*a.x + a.y*a.y + a.z*a.z + a.w*a.w
           + c.x*c.x + c.y*c.y + c.z*c.z + c.w*c.w;
  #pragma unroll
  for (int off = 32; off; off >>= 1) { s += __shfl_xor(s, off); ss += __shfl_xor(ss, off); }
  const float mu = s * (1.0f / 512.0f);
  const float rstd = rsqrtf(ss * (1.0f / 512.0f) - mu * mu + 1e-6f);
  const float4* g4 = (const float4*)g;
  const float4* b4 = (const float4*)bb;
  float4 g0 = g4[lane * 2], g1 = g4[lane * 2 + 1];
  float4 b0 = b4[lane * 2], b1 = b4[lane * 2 + 1];
  usv8 rr;
  rr[0] = f2bf((a.x - mu) * rstd * g0.x + b0.x);
  rr[1] = f2bf((a.y - mu) * rstd * g0.y + b0.y);
  rr[2] = f2bf((a.z - mu) * rstd * g0.z + b0.z);
  rr[3] = f2bf((a.w - mu) * rstd * g0.w + b0.w);
  rr[4] = f2bf((c.x - mu) * rstd * g1.x + b1.x);
  rr[5] = f2bf((c.y - mu) * rstd * g1.y + b1.y);
  rr[6] = f2bf((c.z - mu) * rstd * g1.z + b1.z);
  rr[7] = f2bf((c.w - mu) * rstd * g1.w + b1.w);
  *(usv8*)(out + ((size_t)row << 9) + (lane << 3)) = rr;
}

// ---------------- layernorm (C=512) fp32 in -> bf16 out ----------------
__global__ __launch_bounds__(256) void ln_kernel(
    const float* __restrict__ x, const float* __restrict__ g,
    const float* __restrict__ bb, u16* __restrict__ out)
{
  const int row = (blockIdx.x << 2) + (threadIdx.x >> 6);
  const int lane = threadIdx.x & 63;
  const float4* xr = (const float4*)(x + ((size_t)row << 9));
  float4 a = xr[lane * 2], c = xr[lane * 2 + 1];
  float s  = a.x + a.y + a.z + a.w + c.x + c.y + c.z + c.w;
  float ss = a.x*a.x + a.y*a.y + a.z*a.z + a.w*a.w
           + c.x*c.x + c.y*c.y + c.z*c.z + c.w*c.w;
  #pragma unroll
  for (int off = 32; off; off >>= 1) { s += __shfl_xor(s, off); ss += __shfl_xor(ss, off); }
  const float mu = s * (1.0f / 512.0f);
  const float rstd = rsqrtf(ss * (1.0f / 512.0f) - mu * mu + 1e-6f);
  const float4* g4 = (const float4*)g;
  const float4* b4 = (const float4*)bb;
  float4 g0 = g4[lane * 2], g1 = g4[lane * 2 + 1];
  float4 b0 = b4[lane * 2], b1 = b4[lane * 2 + 1];
  usv8 rr;
  rr[0] = f2bf((a.x - mu) * rstd * g0.x + b0.x);
  rr[1] = f2bf((a.y - mu) * rstd * g0.y + b0.y);
  rr[2] = f2bf((a.z - mu) * rstd * g0.z + b0.z);
  rr[3] = f2bf((a.w - mu) * rstd * g0.w + b0.w);
  rr[4] = f2bf((c.x - mu) * rstd * g1.x + b1.x);
  rr[5] = f2bf((c.y - mu) * rstd * g1.y + b1.y);
  rr[6] = f2bf((c.z - mu) * rstd * g1.z + b1.z);
  rr[7] = f2bf((c.w - mu) * rstd * g1.w + b1.w);
  *(usv8*)(out + ((size_t)row << 9) + (lane << 3)) = rr;
}

// ---------------- GEMM (BK=64): 2-phase dbuf + XOR-swizzled LDS tiles -----
// EPI 0: bf16. EPI 1: f32 acc+bias+res. EPI 2: bf16 gelu. EPI 3: qkv fused:
// Q cols prescaled->qkvb, K cols->qkvb, V cols TRANSPOSED->vt (res = vt).
template<int EPI, int BM, int BN>
__global__ __launch_bounds__(256, (BN == 128) ? 2 : ((BM == 64) ? 4 : 3))
void gemm_kernel(
    const u16* __restrict__ A, const u16* __restrict__ W,
    int K, int Nn, const float* __restrict__ bias,
    const float* __restrict__ res, void* __restrict__ outp)
{
  __shared__ u16 sA[2][BM * 64];
  __shared__ u16 sB[2][BN * 64];
  constexpr int WM = (BN == 128) ? 2 : 4;   // wave-groups along m
  constexpr int MI = BM / (16 * WM);        // 16-row m-frags per wave
  constexpr int SA = BM / 32;               // A 1KB-segments per wave
  constexpr int SB = BN / 32;               // B segments per wave
  const int m0 = blockIdx.x * BM, n0 = blockIdx.y * BN;
  const int lane = threadIdx.x & 63, wave = threadIdx.x >> 6;
  const int wm = (BN == 128) ? (wave >> 1) : wave;
  const int wn = (BN == 128) ? (wave & 1) : 0;
  const int srow = lane >> 3;
  const int scol = ((lane & 7) ^ srow) << 3;    // pre-swizzled source col
  const int l15 = lane & 15, g = lane >> 4;
  const int nk = K >> 6;
  f32x4 acc[MI][4] = {};

  auto stage = [&](int kt, int buf) {
    const int kc = (kt << 6) + scol;
    #pragma unroll
    for (int i = 0; i < SA; ++i) {
      const int c = wave * SA + i;
      gload_lds16(A + (size_t)(m0 + (c << 3) + srow) * K + kc, &sA[buf][c << 9]);
    }
    #pragma unroll
    for (int i = 0; i < SB; ++i) {
      const int c = wave * SB + i;
      gload_lds16(W + (size_t)(n0 + (c << 3) + srow) * K + kc, &sB[buf][c << 9]);
    }
  };

  const int x7 = l15 & 7;   // read-side XOR (row&7 = l15&7 for 16-row frags)
  stage(0, 0);
  int buf = 0;
  for (int kt = 0; kt < nk; ++kt) {
    __syncthreads();               // drains stage(kt); buf^1 reads done
    if (kt + 1 < nk) stage(kt + 1, buf ^ 1);   // in flight across compute
    #pragma unroll
    for (int kk = 0; kk < 2; ++kk) {
      const int gsw = (((kk << 2) + g) ^ x7) << 3;   // swizzled granule (u16)
      sv8 af[MI], bfr[4];
      #pragma unroll
      for (int mi = 0; mi < MI; ++mi)
        af[mi] = *(const sv8*)(&sA[buf][(wm * (16 * MI) + mi * 16 + l15) * 64 + gsw]);
      #pragma unroll
      for (int ni = 0; ni < 4; ++ni)
        bfr[ni] = *(const sv8*)(&sB[buf][(wn * 64 + ni * 16 + l15) * 64 + gsw]);
      #pragma unroll
      for (int mi = 0; mi < MI; ++mi)
        #pragma unroll
        for (int ni = 0; ni < 4; ++ni)
          acc[mi][ni] = mfma16(af[mi], bfr[ni], acc[mi][ni]);
    }
    buf ^= 1;
  }
  float bias_v[4];
  if (EPI == 1 || EPI == 2) {
    #pragma unroll
    for (int ni = 0; ni < 4; ++ni)
      bias_v[ni] = bias[n0 + wn * 64 + ni * 16 + l15];
  }
  #pragma unroll
  for (int mi = 0; mi < MI; ++mi) {
    #pragma unroll
    for (int ni = 0; ni < 4; ++ni) {
      const int gcol = n0 + wn * 64 + ni * 16 + l15;
      const int grow0 = m0 + wm * (16 * MI) + mi * 16 + (g << 2);
      if (EPI == 3 && gcol >= 1024) {
        // V column: store transposed into vt[(b*8+h)*64+d][n], n=grow0..+3
        const int hd = gcol - 1024;
        u16* vtp = (u16*)res;   // res carries vt for EPI 3
        usv4 vv;
        #pragma unroll
        for (int r = 0; r < 4; ++r) vv[r] = f2bf(acc[mi][ni][r]);
        *(usv4*)(vtp + ((size_t)((m0 >> 11) * 512 + hd) * 2048) + (grow0 & 2047)) = vv;
        continue;
      }
      #pragma unroll
      for (int r = 0; r < 4; ++r) {
        const int grow = grow0 + r;
        float v = acc[mi][ni][r];
        if (EPI == 0) {
          ((u16*)outp)[(size_t)grow * Nn + gcol] = f2bf(v);
        } else if (EPI == 3) {
          if (gcol < 512) v *= 0.18033688011112042f;  // 0.125*log2(e)
          ((u16*)outp)[(size_t)grow * Nn + gcol] = f2bf(v);
        } else if (EPI == 1) {
          ((float*)outp)[(size_t)grow * Nn + gcol] =
              v + bias_v[ni] + res[(size_t)grow * Nn + gcol];
        } else {
          ((u16*)outp)[(size_t)grow * Nn + gcol] = f2bf(gelu_f(v + bias_v[ni]));
        }
      }
    }
  }
}

// ---------------- GEMM BK=128 (64x64), XOR-swizzled: 16 MFMAs/phase -------
template<int EPI>
__global__ __launch_bounds__(256, 2) void gemm_k128(
    const u16* __restrict__ A, const u16* __restrict__ W,
    int K, int Nn, const float* __restrict__ bias,
    const float* __restrict__ res, void* __restrict__ outp)
{
  __shared__ u16 sA[2][64 * 128];
  __shared__ u16 sB[2][64 * 128];
  const int m0 = blockIdx.x << 6, n0 = blockIdx.y << 6;
  const int lane = threadIdx.x & 63, wave = threadIdx.x >> 6;
  const int l15 = lane & 15, g = lane >> 4;
  const int rofs = lane >> 4;                  // dest row within 4-row seg
  const int nk = K >> 7;
  f32x4 acc[4] = {};

  auto stage = [&](int kt, int buf) {
    #pragma unroll
    for (int i = 0; i < 4; ++i) {
      const int c = (wave << 2) + i;           // seg = rows [4c, 4c+4)
      const int swz = ((lane & 15) ^ ((i << 2) | rofs)) << 3;  // src col (u16)
      const int kc = (kt << 7) + swz;
      gload_lds16(A + (size_t)(m0 + (c << 2) + rofs) * K + kc, &sA[buf][c << 9]);
      gload_lds16(W + (size_t)(n0 + (c << 2) + rofs) * K + kc, &sB[buf][c << 9]);
    }
  };

  stage(0, 0);
  int buf = 0;
  for (int kt = 0; kt < nk; ++kt) {
    __syncthreads();
    if (kt + 1 < nk) stage(kt + 1, buf ^ 1);
    #pragma unroll
    for (int kk = 0; kk < 4; ++kk) {
      const int gsw = ((((kk << 2) + g) ^ l15)) << 3;   // granule ^ row&15
      sv8 af = *(const sv8*)(&sA[buf][((wave << 4) + l15) * 128 + gsw]);
      #pragma unroll
      for (int ni = 0; ni < 4; ++ni) {
        sv8 bfr = *(const sv8*)(&sB[buf][(ni * 16 + l15) * 128 + gsw]);
        acc[ni] = mfma16(af, bfr, acc[ni]);
      }
    }
    buf ^= 1;
  }
  float bias_v[4];
  if (EPI == 1 || EPI == 2) {
    #pragma unroll
    for (int ni = 0; ni < 4; ++ni)
      bias_v[ni] = bias[n0 + ni * 16 + l15];
  }
  #pragma unroll
  for (int ni = 0; ni < 4; ++ni) {
    const int gcol = n0 + ni * 16 + l15;
    #pragma unroll
    for (int r = 0; r < 4; ++r) {
      const int grow = m0 + (wave << 4) + (g << 2) + r;
      float v = acc[ni][r];
      if (EPI == 0) {
        ((u16*)outp)[(size_t)grow * Nn + gcol] = f2bf(v);
      } else if (EPI == 1) {
        ((float*)outp)[(size_t)grow * Nn + gcol] =
            v + bias_v[ni] + res[(size_t)grow * Nn + gcol];
      } else {
        ((u16*)outp)[(size_t)grow * Nn + gcol] = f2bf(gelu_f(v + bias_v[ni]));
      }
    }
  }
}

// ---------------- proj GEMM: BK=128 + fused 4-partial combine on A --------
// A = pt0+pt1+pt2+pt3 (bf16 [4096][512] each), summed during reg-staging,
// written to the same swizzled LDS layout. B via gload_lds. Out f32 =
// acc + bias + res. Grid (64, 8), K=512 -> 4 phases.
__global__ __launch_bounds__(256, 2) void gemm_proj(
    const u16* __restrict__ p0, const u16* __restrict__ p1,
    const u16* __restrict__ p2, const u16* __restrict__ p3,
    const u16* __restrict__ W, const float* __restrict__ bias,
    const float* __restrict__ res, float* __restrict__ outp)
{
  __shared__ u16 sA[2][64 * 128];
  __shared__ u16 sB[2][64 * 128];
  const int m0 = blockIdx.x << 6, n0 = blockIdx.y << 6;
  const int lane = threadIdx.x & 63, wave = threadIdx.x >> 6;
  const int l15 = lane & 15, g = lane >> 4;
  const int rofs = lane >> 4;
  f32x4 acc[4] = {};

  auto stage = [&](int kt, int buf) {
    #pragma unroll
    for (int i = 0; i < 4; ++i) {            // B via async gload
      const int c = (wave << 2) + i;
      const int swz = ((lane & 15) ^ ((i << 2) | rofs)) << 3;
      gload_lds16(W + (size_t)(n0 + (c << 2) + rofs) * 512 + (kt << 7) + swz,
                  &sB[buf][c << 9]);
    }
    #pragma unroll
    for (int i = 0; i < 4; ++i) {            // A = sum of 4 partials, reg-staged
      const int c = (wave << 2) + i;
      const int swz = ((lane & 15) ^ ((i << 2) | rofs)) << 3;
      const size_t off = (size_t)(m0 + (c << 2) + rofs) * 512 + (kt << 7) + swz;
      usv8 a0 = *(const usv8*)(p0 + off);
      usv8 a1 = *(const usv8*)(p1 + off);
      usv8 a2 = *(const usv8*)(p2 + off);
      usv8 a3 = *(const usv8*)(p3 + off);
      usv8 w;
      #pragma unroll
      for (int j = 0; j < 8; ++j)
        w[j] = f2bf((bf2f(a0[j]) + bf2f(a1[j])) + (bf2f(a2[j]) + bf2f(a3[j])));
      *(usv8*)(&sA[buf][(c << 9) + (lane << 3)]) = w;
    }
  };

  stage(0, 0);
  int buf = 0;
  for (int kt = 0; kt < 4; ++kt) {
    __syncthreads();
    if (kt + 1 < 4) stage(kt + 1, buf ^ 1);
    #pragma unroll
    for (int kk = 0; kk < 4; ++kk) {
      const int gsw = ((((kk << 2) + g) ^ l15)) << 3;
      sv8 af = *(const sv8*)(&sA[buf][((wave << 4) + l15) * 128 + gsw]);
      #pragma unroll
      for (int ni = 0; ni < 4; ++ni) {
        sv8 bfr = *(const sv8*)(&sB[buf][(ni * 16 + l15) * 128 + gsw]);
        acc[ni] = mfma16(af, bfr, acc[ni]);
      }
    }
    buf ^= 1;
  }
  float bias_v[4];
  #pragma unroll
  for (int ni = 0; ni < 4; ++ni) bias_v[ni] = bias[n0 + ni * 16 + l15];
  #pragma unroll
  for (int ni = 0; ni < 4; ++ni) {
    const int gcol = n0 + ni * 16 + l15;
    #pragma unroll
    for (int r = 0; r < 4; ++r) {
      const int grow = m0 + (wave << 4) + (g << 2) + r;
      outp[(size_t)grow * 512 + gcol] =
          acc[ni][r] + bias_v[ni] + res[(size_t)grow * 512 + gcol];
    }
  }
}

// ---------------- fused attention v8.2 (softmax over heads) ----------------
// 256 blocks x 512 thr (8 waves = 2 quads x 4 roles). Block = 64 n-rows x
// 512-m quarter; 16 tiles of 32 m. r12 barrier structure; running stage
// pointers + hoisted LDS offsets + setprio.
__global__ __launch_bounds__(512, 2) void attn_kernel(
    const u16* __restrict__ qkvb, const u16* __restrict__ vt,
    u16* __restrict__ p0, u16* __restrict__ p1,
    u16* __restrict__ p2, u16* __restrict__ p3)
{
  __shared__ u16 sK[8 * 32 * 64];       // 32KB [h][m32][slot8], slot^=(m&7)
  __shared__ u16 sV[512 * 32];          // 32KB [h*64+d][slot4], slot^=((row>>1)&3)
  __shared__ u32 sSum[2 * 4 * 4 * 128]; // 16KB [q2][mn][role][lane*2+half]
  const int tid = threadIdx.x;
  const int lane = tid & 63, w = tid >> 6;     // w 0..7
  const int q2 = w >> 2, role = w & 3;
  const int l15 = lane & 15, g = lane >> 4;

  const int pair = blockIdx.x & 7;     // XCD-pinned (b, msplit)
  const int b = pair >> 2;
  const int msplit = pair & 3;
  const int strip = blockIdx.x >> 3;   // 0..31
  const int row0 = b * 2048 + strip * 64 + q2 * 32;  // global flat row
  const int m0 = msplit << 9;          // m-offset within batch; 16 tiles of 32
  u16* pbuf = (msplit < 2) ? (msplit ? p1 : p0) : ((msplit == 2) ? p2 : p3);

  // ---- Q hoist: head h0=2*role+hp, rows row0+ns*16+l15 (pre-scaled) ----
  sv8 Q[2][2][2];
  #pragma unroll
  for (int hp = 0; hp < 2; ++hp)
    #pragma unroll
    for (int ns = 0; ns < 2; ++ns) {
      const u16* qp = qkvb + (size_t)(row0 + ns * 16 + l15) * 1536
                    + (role * 2 + hp) * 64 + g * 8;
      Q[hp][ns][0] = *(const sv8*)qp;
      Q[hp][ns][1] = *(const sv8*)(qp + 32);
    }

  // ---- hoisted LDS read offsets (u16 units) ----
  int kOff[2][2][2], vOff[2][4];
  {
    const int x7 = l15 & 7;
    #pragma unroll
    for (int hp = 0; hp < 2; ++hp) {
      #pragma unroll
      for (int ms = 0; ms < 2; ++ms) {
        const int row = ((role * 2 + hp) * 32 + ms * 16 + l15) * 64;
        kOff[hp][ms][0] = row + (g ^ x7) * 8;
        kOff[hp][ms][1] = row + ((4 + g) ^ x7) * 8;
      }
      const int xv = (l15 >> 1) & 3;
      #pragma unroll
      for (int dsub = 0; dsub < 4; ++dsub)
        vOff[hp][dsub] = ((role * 2 + hp) * 64 + dsub * 16 + l15) * 32 + (g ^ xv) * 8;
    }
  }

  // staging bases (pre-swizzled global sources, linear LDS dst)
  const u16* pK = qkvb + (size_t)(b * 2048 + m0 + (lane >> 3)) * 1536 + 512
                + w * 64 + ((lane & 7) ^ (lane >> 3)) * 8;
  const u16* pV = vt + (size_t)(b * 512 + w * 64 + (lane >> 2)) * 2048 + m0
                + ((lane & 3) ^ ((lane >> 3) & 3)) * 8;

  float pe_f[2][2][2][4];   // [hp][ms][ns][r] e-values
  sv8 pf[2][2];             // P^T A-frags [hp][ns]
  f32x4 acc[2][4][2] = {};
  u32* mySum = sSum + (q2 << 11) + (role << 7) + lane * 2;
  const u32* rdSum = sSum + (q2 << 11) + lane * 2;

  const u16* pKrun = pK;    // running pointers (no per-tile 64b muls)
  const u16* pVrun = pV;

  auto stageK = [&]() {
    #pragma unroll
    for (int i = 0; i < 4; ++i)
      gload_lds16(pKrun + i * 12288, sK + ((w << 2) + i) * 512);
    pKrun += 32 * 1536;
  };
  auto stageV = [&]() {
    #pragma unroll
    for (int i = 0; i < 4; ++i)
      gload_lds16(pVrun + (size_t)i * 32768, sV + ((w << 2) + i) * 512);
    pVrun += 32;
  };
  // QK^T for own 2 heads -> exp2 (Q pre-scaled) -> pe_f + b64 sums -> LDS
  auto qk_step = [&]() {
    __builtin_amdgcn_s_setprio(1);
    #pragma unroll
    for (int hp = 0; hp < 2; ++hp)
      #pragma unroll
      for (int ms = 0; ms < 2; ++ms) {
        sv8 k0 = *(const sv8*)(sK + kOff[hp][ms][0]);
        sv8 k1 = *(const sv8*)(sK + kOff[hp][ms][1]);
        #pragma unroll
        for (int ns = 0; ns < 2; ++ns) {
          f32x4 s = {0.f, 0.f, 0.f, 0.f};
          s = mfma16(k0, Q[hp][ns][0], s);
          s = mfma16(k1, Q[hp][ns][1], s);
          #pragma unroll
          for (int r = 0; r < 4; ++r)
            pe_f[hp][ms][ns][r] = __builtin_amdgcn_exp2f(s[r]);
        }
      }
    __builtin_amdgcn_s_setprio(0);
    #pragma unroll
    for (int ms = 0; ms < 2; ++ms)
      #pragma unroll
      for (int ns = 0; ns < 2; ++ns) {
        const int mn = ms * 2 + ns;
        u32x2 v2;
        v2.x = pkbf(pe_f[0][ms][ns][0] + pe_f[1][ms][ns][0],
                    pe_f[0][ms][ns][1] + pe_f[1][ms][ns][1]);
        v2.y = pkbf(pe_f[0][ms][ns][2] + pe_f[1][ms][ns][2],
                    pe_f[0][ms][ns][3] + pe_f[1][ms][ns][3]);
        *(u32x2*)(mySum + (mn << 9)) = v2;
      }
  };
  // read quad's 4 roles' sums (b64) -> inv; normalize -> pack -> permlane
  auto build_pf = [&]() {
    float inv[2][2][4];
    #pragma unroll
    for (int ms = 0; ms < 2; ++ms)
      #pragma unroll
      for (int ns = 0; ns < 2; ++ns) {
        const int mn = ms * 2 + ns;
        float t0 = 0.f, t1 = 0.f, t2 = 0.f, t3 = 0.f;
        #pragma unroll
        for (int p = 0; p < 4; ++p) {
          u32x2 v = *(const u32x2*)(rdSum + (mn << 9) + (p << 7));
          t0 += __builtin_bit_cast(float, v.x << 16);
          t1 += __builtin_bit_cast(float, v.x & 0xffff0000u);
          t2 += __builtin_bit_cast(float, v.y << 16);
          t3 += __builtin_bit_cast(float, v.y & 0xffff0000u);
        }
        inv[ms][ns][0] = __builtin_amdgcn_rcpf(t0);
        inv[ms][ns][1] = __builtin_amdgcn_rcpf(t1);
        inv[ms][ns][2] = __builtin_amdgcn_rcpf(t2);
        inv[ms][ns][3] = __builtin_amdgcn_rcpf(t3);
      }
    #pragma unroll
    for (int hp = 0; hp < 2; ++hp)
      #pragma unroll
      for (int ns = 0; ns < 2; ++ns) {
        float p[8];
        #pragma unroll
        for (int ms = 0; ms < 2; ++ms)
          #pragma unroll
          for (int r = 0; r < 4; ++r)
            p[ms * 4 + r] = pe_f[hp][ms][ns][r] * inv[ms][ns][r];
        u32 pa = pkbf(p[0], p[1]), pc = pkbf(p[2], p[3]);
        u32 pb_ = pkbf(p[4], p[5]), pd = pkbf(p[6], p[7]);
        asm("v_permlane32_swap_b32 %0, %1" : "+v"(pa), "+v"(pb_));
        asm("v_permlane16_swap_b32 %0, %1" : "+v"(pa), "+v"(pb_));
        asm("v_permlane32_swap_b32 %0, %1" : "+v"(pc), "+v"(pd));
        asm("v_permlane16_swap_b32 %0, %1" : "+v"(pc), "+v"(pd));
        u32x4 pw; pw.x = pa; pw.y = pc; pw.z = pb_; pw.w = pd;
        pf[hp][ns] = __builtin_bit_cast(sv8, pw);
      }
  };
  auto do_pv = [&]() {
    __builtin_amdgcn_s_setprio(1);
    #pragma unroll
    for (int hp = 0; hp < 2; ++hp)
      #pragma unroll
      for (int dsub = 0; dsub < 4; ++dsub) {
        sv8 vf = *(const sv8*)(sV + vOff[hp][dsub]);
        #pragma unroll
        for (int ns = 0; ns < 2; ++ns)
          acc[hp][dsub][ns] = mfma16(pf[hp][ns], vf, acc[hp][dsub][ns]);
      }
    __builtin_amdgcn_s_setprio(0);
  };

  stageK(); stageV();
  __syncthreads();                 // drain stage(0)
  qk_step();                       // tile 0 scores + sums
  for (int t = 0; t < 16; ++t) {
    __syncthreads();               // B2: sums(t) visible, V(t) drained
    if (t < 15) stageK();          // K(t+1), in flight under pf-build + PV
    build_pf();
    do_pv();
    __syncthreads();               // B3: K(t+1) drained, sV/sSum free
    if (t < 15) { stageV(); qk_step(); }  // V(t+1) in flight under next QK
  }
  // ---- store partials (plain bf16, no atomics) ----
  #pragma unroll
  for (int hp = 0; hp < 2; ++hp)
    #pragma unroll
    for (int dsub = 0; dsub < 4; ++dsub)
      #pragma unroll
      for (int ns = 0; ns < 2; ++ns)
        #pragma unroll
        for (int r = 0; r < 4; ++r)
          pbuf[(size_t)(row0 + ns * 16 + g * 4 + r) * 512
               + (role * 2 + hp) * 64 + dsub * 16 + l15] = f2bf(acc[hp][dsub][ns][r]);
}

extern "C" void kernel_launch(void* const* d_in, const int* in_sizes, int n_in,
                              void* d_out, int out_size, void* d_ws, size_t ws_size,
                              hipStream_t stream) {
  const float* x      = (const float*)d_in[0];
  const float* ln_g   = (const float*)d_in[1];
  const float* ln_b   = (const float*)d_in[2];
  const float* qkv_w  = (const float*)d_in[3];
  const float* proj_w = (const float*)d_in[4];
  const float* proj_b = (const float*)d_in[5];
  const float* fc1_w  = (const float*)d_in[6];
  const float* fc1_b  = (const float*)d_in[7];
  const float* fc2_w  = (const float*)d_in[8];
  const float* fc2_b  = (const float*)d_in[9];
  char* ws = (char*)d_ws;
  u16*   w_qkv  = (u16*)(ws + 0);         // 1536x512 bf16
  u16*   w_proj = (u16*)(ws + 1572864);   // 512x512
  u16*   w_fc1  = (u16*)(ws + 2097152);   // 2048x512
  u16*   w_fc2  = (u16*)(ws + 4194304);   // 512x2048
  u16*   xn     = (u16*)(ws + 6291456);   // 4096x512 bf16 (LN out; reused as pt0)
  u16*   qkvb   = (u16*)(ws + 10485760);  // 4096x1536 bf16 (V third unused)
  u16*   vtb    = (u16*)(ws + 23068672);  // [2][8][64][2048] bf16
  float* x1     = (float*)(ws + 39845888);// 4096x512 f32
  u16*   hbuf   = (u16*)(ws + 48234496);  // 4096x2048 bf16 (pt1..pt3 pre-fc1)

  u16* pt0 = xn;                 // free after qkv GEMM consumes xn
  u16* pt1 = hbuf;               // hbuf free until fc1
  u16* pt2 = hbuf + 2097152;
  u16* pt3 = hbuf + 4194304;

  prep_kernel<<<4096, 256, 0, stream>>>(qkv_w, proj_w, fc1_w, fc2_w,
                                        w_qkv, w_proj, w_fc1, w_fc2,
                                        x, ln_g, ln_b, xn);
  gemm_kernel<3, 128, 64><<<dim3(32, 24), 256, 0, stream>>>(
      xn, w_qkv, 512, 1536, nullptr, (const float*)vtb, qkvb);
  attn_kernel<<<256, 512, 0, stream>>>(qkvb, vtb, pt0, pt1, pt2, pt3);
  gemm_proj<<<dim3(64, 8), 256, 0, stream>>>(
      pt0, pt1, pt2, pt3, w_proj, proj_b, x, x1);
  ln_kernel<<<1024, 256, 0, stream>>>(x1, ln_g, ln_b, xn);
  gemm_kernel<2, 128, 128><<<dim3(32, 16), 256, 0, stream>>>(
      xn, w_fc1, 512, 2048, fc1_b, nullptr, hbuf);
  gemm_k128<1><<<dim3(64, 8), 256, 0, stream>>>(
      hbuf, w_fc2, 2048, 512, fc2_b, x1, d_out);
}

// Round 22
// 111.387 us; speedup vs baseline: 1.0208x; 1.0208x over previous
//
#include <hip/hip_runtime.h>

// Transformer layer, MI355X/gfx950.
// B=2, N=2048, C=512, H=8, D=64. Softmax over HEAD axis (faithful to ref).
// r22 = r20 best config (112.9us): attn v8.2 WITHOUT setprio (m190: setprio
// hurts barrier-lockstep kernels; r12 no-setprio measured 44.5 vs 45.5 with),
// XOR-swizzled 2-phase GEMMs (BK=64 qkv/fc1, BK=128 proj/fc2), qkv epilogue
// writes V transposed to vt, cmb4 combine.

typedef unsigned short u16;
typedef unsigned int u32;
typedef __attribute__((ext_vector_type(4))) float f32x4;
typedef __attribute__((ext_vector_type(4))) u32 u32x4;
typedef __attribute__((ext_vector_type(2))) u32 u32x2;
typedef __attribute__((ext_vector_type(8))) short sv8;
typedef __attribute__((ext_vector_type(8))) __bf16 bfv8;
typedef __attribute__((ext_vector_type(8))) u16 usv8;
typedef __attribute__((ext_vector_type(4))) u16 usv4;

#define DEV static __device__ __forceinline__

DEV u16 f2bf(float f) {  // RNE fp32 -> bf16
  u32 x = __builtin_bit_cast(u32, f);
  return (u16)((x + 0x7fffu + ((x >> 16) & 1u)) >> 16);
}

DEV float bf2f(u16 v) { return __builtin_bit_cast(float, (u32)v << 16); }

DEV f32x4 mfma16(sv8 a, sv8 b, f32x4 c) {
  return __builtin_amdgcn_mfma_f32_16x16x32_bf16(
      __builtin_bit_cast(bfv8, a), __builtin_bit_cast(bfv8, b), c, 0, 0, 0);
}

DEV void gload_lds16(const void* g, void* l) {
  __builtin_amdgcn_global_load_lds(
      (const __attribute__((address_space(1))) u32*)g,
      (__attribute__((address_space(3))) u32*)l, 16, 0, 0);
}

DEV u32 pkbf(float a, float b) {
  u32 r;
  asm("v_cvt_pk_bf16_f32 %0, %1, %2" : "=v"(r) : "v"(a), "v"(b));
  return r;
}

DEV float gelu_f(float t) {
  // tanh-form GELU: 0.5t(1+tanh(0.79788456(t+0.044715t^3))); |err| < 3e-3
  const float u = t * (0.7978845608028654f + 0.03567740814183556f * t * t);
  const float e = __builtin_amdgcn_exp2f(u * 2.8853900817779268f);  // e^(2u)
  const float th = 1.0f - 2.0f * __builtin_amdgcn_rcpf(e + 1.0f);
  return 0.5f * t * (1.0f + th);
}

// ---------------- prep: weight cast (blocks 0..3071) + LN1 (3072..4095) ----
__global__ __launch_bounds__(256) void prep_kernel(
    const float* __restrict__ s0, const float* __restrict__ s1,
    const float* __restrict__ s2, const float* __restrict__ s3,
    u16* __restrict__ d0, u16* __restrict__ d1,
    u16* __restrict__ d2, u16* __restrict__ d3,
    const float* __restrict__ x, const float* __restrict__ g,
    const float* __restrict__ bb, u16* __restrict__ out)
{
  if (blockIdx.x < 3072) {
    int i = blockIdx.x * 256 + threadIdx.x;  // vec4 index, 786432 total
    const float* s; u16* d; int off;
    if (i < 196608)      { s = s0; d = d0; off = i; }
    else if (i < 262144) { s = s1; d = d1; off = i - 196608; }
    else if (i < 524288) { s = s2; d = d2; off = i - 262144; }
    else                 { s = s3; d = d3; off = i - 524288; }
    float4 v = ((const float4*)s)[off];
    usv4 r; r.x = f2bf(v.x); r.y = f2bf(v.y); r.z = f2bf(v.z); r.w = f2bf(v.w);
    *(usv4*)(d + (size_t)off * 4) = r;
    return;
  }
  const int row = ((blockIdx.x - 3072) << 2) + (threadIdx.x >> 6);
  const int lane = threadIdx.x & 63;
  const float4* xr = (const float4*)(x + ((size_t)row << 9));
  float4 a = xr[lane * 2], c = xr[lane * 2 + 1];
  float s  = a.x + a.y + a.z + a.w + c.x + c.y + c.z + c.w;
  float ss = a.x*a.x + a.y*a.y + a.z*a.z + a.w*a.w
           + c.x*c.x + c.y*c.y + c.z*c.z + c.w*c.w;
  #pragma unroll
  for (int off = 32; off; off >>= 1) { s += __shfl_xor(s, off); ss += __shfl_xor(ss, off); }
  const float mu = s * (1.0f / 512.0f);
  const float rstd = rsqrtf(ss * (1.0f / 512.0f) - mu * mu + 1e-6f);
  const float4* g4 = (const float4*)g;
  const float4* b4 = (const float4*)bb;
  float4 g0 = g4[lane * 2], g1 = g4[lane * 2 + 1];
  float4 b0 = b4[lane * 2], b1 = b4[lane * 2 + 1];
  usv8 rr;
  rr[0] = f2bf((a.x - mu) * rstd * g0.x + b0.x);
  rr[1] = f2bf((a.y - mu) * rstd * g0.y + b0.y);
  rr[2] = f2bf((a.z - mu) * rstd * g0.z + b0.z);
  rr[3] = f2bf((a.w - mu) * rstd * g0.w + b0.w);
  rr[4] = f2bf((c.x - mu) * rstd * g1.x + b1.x);
  rr[5] = f2bf((c.y - mu) * rstd * g1.y + b1.y);
  rr[6] = f2bf((c.z - mu) * rstd * g1.z + b1.z);
  rr[7] = f2bf((c.w - mu) * rstd * g1.w + b1.w);
  *(usv8*)(out + ((size_t)row << 9) + (lane << 3)) = rr;
}

// ---------------- layernorm (C=512) fp32 in -> bf16 out ----------------
__global__ __launch_bounds__(256) void ln_kernel(
    const float* __restrict__ x, const float* __restrict__ g,
    const float* __restrict__ bb, u16* __restrict__ out)
{
  const int row = (blockIdx.x << 2) + (threadIdx.x >> 6);
  const int lane = threadIdx.x & 63;
  const float4* xr = (const float4*)(x + ((size_t)row << 9));
  float4 a = xr[lane * 2], c = xr[lane * 2 + 1];
  float s  = a.x + a.y + a.z + a.w + c.x + c.y + c.z + c.w;
  float ss = a.x*a.x + a.y*a.y + a.z*a.z + a.w*a.w
           + c.x*c.x + c.y*c.y + c.z*c.z + c.w*c.w;
  #pragma unroll
  for (int off = 32; off; off >>= 1) { s += __shfl_xor(s, off); ss += __shfl_xor(ss, off); }
  const float mu = s * (1.0f / 512.0f);
  const float rstd = rsqrtf(ss * (1.0f / 512.0f) - mu * mu + 1e-6f);
  const float4* g4 = (const float4*)g;
  const float4* b4 = (const float4*)bb;
  float4 g0 = g4[lane * 2], g1 = g4[lane * 2 + 1];
  float4 b0 = b4[lane * 2], b1 = b4[lane * 2 + 1];
  usv8 rr;
  rr[0] = f2bf((a.x - mu) * rstd * g0.x + b0.x);
  rr[1] = f2bf((a.y - mu) * rstd * g0.y + b0.y);
  rr[2] = f2bf((a.z - mu) * rstd * g0.z + b0.z);
  rr[3] = f2bf((a.w - mu) * rstd * g0.w + b0.w);
  rr[4] = f2bf((c.x - mu) * rstd * g1.x + b1.x);
  rr[5] = f2bf((c.y - mu) * rstd * g1.y + b1.y);
  rr[6] = f2bf((c.z - mu) * rstd * g1.z + b1.z);
  rr[7] = f2bf((c.w - mu) * rstd * g1.w + b1.w);
  *(usv8*)(out + ((size_t)row << 9) + (lane << 3)) = rr;
}

// ---------------- GEMM (BK=64): 2-phase dbuf + XOR-swizzled LDS tiles -----
// EPI 0: bf16. EPI 1: f32 acc+bias+res. EPI 2: bf16 gelu. EPI 3: qkv fused:
// Q cols prescaled->qkvb, K cols->qkvb, V cols TRANSPOSED->vt (res = vt).
template<int EPI, int BM, int BN>
__global__ __launch_bounds__(256, (BN == 128) ? 2 : ((BM == 64) ? 4 : 3))
void gemm_kernel(
    const u16* __restrict__ A, const u16* __restrict__ W,
    int K, int Nn, const float* __restrict__ bias,
    const float* __restrict__ res, void* __restrict__ outp)
{
  __shared__ u16 sA[2][BM * 64];
  __shared__ u16 sB[2][BN * 64];
  constexpr int WM = (BN == 128) ? 2 : 4;   // wave-groups along m
  constexpr int MI = BM / (16 * WM);        // 16-row m-frags per wave
  constexpr int SA = BM / 32;               // A 1KB-segments per wave
  constexpr int SB = BN / 32;               // B segments per wave
  const int m0 = blockIdx.x * BM, n0 = blockIdx.y * BN;
  const int lane = threadIdx.x & 63, wave = threadIdx.x >> 6;
  const int wm = (BN == 128) ? (wave >> 1) : wave;
  const int wn = (BN == 128) ? (wave & 1) : 0;
  const int srow = lane >> 3;
  const int scol = ((lane & 7) ^ srow) << 3;    // pre-swizzled source col
  const int l15 = lane & 15, g = lane >> 4;
  const int nk = K >> 6;
  f32x4 acc[MI][4] = {};

  auto stage = [&](int kt, int buf) {
    const int kc = (kt << 6) + scol;
    #pragma unroll
    for (int i = 0; i < SA; ++i) {
      const int c = wave * SA + i;
      gload_lds16(A + (size_t)(m0 + (c << 3) + srow) * K + kc, &sA[buf][c << 9]);
    }
    #pragma unroll
    for (int i = 0; i < SB; ++i) {
      const int c = wave * SB + i;
      gload_lds16(W + (size_t)(n0 + (c << 3) + srow) * K + kc, &sB[buf][c << 9]);
    }
  };

  const int x7 = l15 & 7;   // read-side XOR (row&7 = l15&7 for 16-row frags)
  stage(0, 0);
  int buf = 0;
  for (int kt = 0; kt < nk; ++kt) {
    __syncthreads();               // drains stage(kt); buf^1 reads done
    if (kt + 1 < nk) stage(kt + 1, buf ^ 1);   // in flight across compute
    #pragma unroll
    for (int kk = 0; kk < 2; ++kk) {
      const int gsw = (((kk << 2) + g) ^ x7) << 3;   // swizzled granule (u16)
      sv8 af[MI], bfr[4];
      #pragma unroll
      for (int mi = 0; mi < MI; ++mi)
        af[mi] = *(const sv8*)(&sA[buf][(wm * (16 * MI) + mi * 16 + l15) * 64 + gsw]);
      #pragma unroll
      for (int ni = 0; ni < 4; ++ni)
        bfr[ni] = *(const sv8*)(&sB[buf][(wn * 64 + ni * 16 + l15) * 64 + gsw]);
      #pragma unroll
      for (int mi = 0; mi < MI; ++mi)
        #pragma unroll
        for (int ni = 0; ni < 4; ++ni)
          acc[mi][ni] = mfma16(af[mi], bfr[ni], acc[mi][ni]);
    }
    buf ^= 1;
  }
  float bias_v[4];
  if (EPI == 1 || EPI == 2) {
    #pragma unroll
    for (int ni = 0; ni < 4; ++ni)
      bias_v[ni] = bias[n0 + wn * 64 + ni * 16 + l15];
  }
  #pragma unroll
  for (int mi = 0; mi < MI; ++mi) {
    #pragma unroll
    for (int ni = 0; ni < 4; ++ni) {
      const int gcol = n0 + wn * 64 + ni * 16 + l15;
      const int grow0 = m0 + wm * (16 * MI) + mi * 16 + (g << 2);
      if (EPI == 3 && gcol >= 1024) {
        // V column: store transposed into vt[(b*8+h)*64+d][n], n=grow0..+3
        const int hd = gcol - 1024;
        u16* vtp = (u16*)res;   // res carries vt for EPI 3
        usv4 vv;
        #pragma unroll
        for (int r = 0; r < 4; ++r) vv[r] = f2bf(acc[mi][ni][r]);
        *(usv4*)(vtp + ((size_t)((m0 >> 11) * 512 + hd) * 2048) + (grow0 & 2047)) = vv;
        continue;
      }
      #pragma unroll
      for (int r = 0; r < 4; ++r) {
        const int grow = grow0 + r;
        float v = acc[mi][ni][r];
        if (EPI == 0) {
          ((u16*)outp)[(size_t)grow * Nn + gcol] = f2bf(v);
        } else if (EPI == 3) {
          if (gcol < 512) v *= 0.18033688011112042f;  // 0.125*log2(e)
          ((u16*)outp)[(size_t)grow * Nn + gcol] = f2bf(v);
        } else if (EPI == 1) {
          ((float*)outp)[(size_t)grow * Nn + gcol] =
              v + bias_v[ni] + res[(size_t)grow * Nn + gcol];
        } else {
          ((u16*)outp)[(size_t)grow * Nn + gcol] = f2bf(gelu_f(v + bias_v[ni]));
        }
      }
    }
  }
}

// ---------------- GEMM BK=128 (64x64), XOR-swizzled: 16 MFMAs/phase -------
template<int EPI>
__global__ __launch_bounds__(256, 2) void gemm_k128(
    const u16* __restrict__ A, const u16* __restrict__ W,
    int K, int Nn, const float* __restrict__ bias,
    const float* __restrict__ res, void* __restrict__ outp)
{
  __shared__ u16 sA[2][64 * 128];
  __shared__ u16 sB[2][64 * 128];
  const int m0 = blockIdx.x << 6, n0 = blockIdx.y << 6;
  const int lane = threadIdx.x & 63, wave = threadIdx.x >> 6;
  const int l15 = lane & 15, g = lane >> 4;
  const int rofs = lane >> 4;                  // dest row within 4-row seg
  const int nk = K >> 7;
  f32x4 acc[4] = {};

  auto stage = [&](int kt, int buf) {
    #pragma unroll
    for (int i = 0; i < 4; ++i) {
      const int c = (wave << 2) + i;           // seg = rows [4c, 4c+4)
      const int swz = ((lane & 15) ^ ((i << 2) | rofs)) << 3;  // src col (u16)
      const int kc = (kt << 7) + swz;
      gload_lds16(A + (size_t)(m0 + (c << 2) + rofs) * K + kc, &sA[buf][c << 9]);
      gload_lds16(W + (size_t)(n0 + (c << 2) + rofs) * K + kc, &sB[buf][c << 9]);
    }
  };

  stage(0, 0);
  int buf = 0;
  for (int kt = 0; kt < nk; ++kt) {
    __syncthreads();
    if (kt + 1 < nk) stage(kt + 1, buf ^ 1);
    #pragma unroll
    for (int kk = 0; kk < 4; ++kk) {
      const int gsw = ((((kk << 2) + g) ^ l15)) << 3;   // granule ^ row&15
      sv8 af = *(const sv8*)(&sA[buf][((wave << 4) + l15) * 128 + gsw]);
      #pragma unroll
      for (int ni = 0; ni < 4; ++ni) {
        sv8 bfr = *(const sv8*)(&sB[buf][(ni * 16 + l15) * 128 + gsw]);
        acc[ni] = mfma16(af, bfr, acc[ni]);
      }
    }
    buf ^= 1;
  }
  float bias_v[4];
  if (EPI == 1 || EPI == 2) {
    #pragma unroll
    for (int ni = 0; ni < 4; ++ni)
      bias_v[ni] = bias[n0 + ni * 16 + l15];
  }
  #pragma unroll
  for (int ni = 0; ni < 4; ++ni) {
    const int gcol = n0 + ni * 16 + l15;
    #pragma unroll
    for (int r = 0; r < 4; ++r) {
      const int grow = m0 + (wave << 4) + (g << 2) + r;
      float v = acc[ni][r];
      if (EPI == 0) {
        ((u16*)outp)[(size_t)grow * Nn + gcol] = f2bf(v);
      } else if (EPI == 1) {
        ((float*)outp)[(size_t)grow * Nn + gcol] =
            v + bias_v[ni] + res[(size_t)grow * Nn + gcol];
      } else {
        ((u16*)outp)[(size_t)grow * Nn + gcol] = f2bf(gelu_f(v + bias_v[ni]));
      }
    }
  }
}

// ---------------- fused attention v8.3 (softmax over heads) ----------------
// 256 blocks x 512 thr (8 waves = 2 quads x 4 roles). Block = 64 n-rows x
// 512-m quarter; 16 tiles of 32 m. r12 barrier structure; running stage
// pointers + hoisted LDS offsets. NO setprio (hurts lockstep waves, m190).
__global__ __launch_bounds__(512, 2) void attn_kernel(
    const u16* __restrict__ qkvb, const u16* __restrict__ vt,
    u16* __restrict__ p0, u16* __restrict__ p1,
    u16* __restrict__ p2, u16* __restrict__ p3)
{
  __shared__ u16 sK[8 * 32 * 64];       // 32KB [h][m32][slot8], slot^=(m&7)
  __shared__ u16 sV[512 * 32];          // 32KB [h*64+d][slot4], slot^=((row>>1)&3)
  __shared__ u32 sSum[2 * 4 * 4 * 128]; // 16KB [q2][mn][role][lane*2+half]
  const int tid = threadIdx.x;
  const int lane = tid & 63, w = tid >> 6;     // w 0..7
  const int q2 = w >> 2, role = w & 3;
  const int l15 = lane & 15, g = lane >> 4;

  const int pair = blockIdx.x & 7;     // XCD-pinned (b, msplit)
  const int b = pair >> 2;
  const int msplit = pair & 3;
  const int strip = blockIdx.x >> 3;   // 0..31
  const int row0 = b * 2048 + strip * 64 + q2 * 32;  // global flat row
  const int m0 = msplit << 9;          // m-offset within batch; 16 tiles of 32
  u16* pbuf = (msplit < 2) ? (msplit ? p1 : p0) : ((msplit == 2) ? p2 : p3);

  // ---- Q hoist: head h0=2*role+hp, rows row0+ns*16+l15 (pre-scaled) ----
  sv8 Q[2][2][2];
  #pragma unroll
  for (int hp = 0; hp < 2; ++hp)
    #pragma unroll
    for (int ns = 0; ns < 2; ++ns) {
      const u16* qp = qkvb + (size_t)(row0 + ns * 16 + l15) * 1536
                    + (role * 2 + hp) * 64 + g * 8;
      Q[hp][ns][0] = *(const sv8*)qp;
      Q[hp][ns][1] = *(const sv8*)(qp + 32);
    }

  // ---- hoisted LDS read offsets (u16 units) ----
  int kOff[2][2][2], vOff[2][4];
  {
    const int x7 = l15 & 7;
    #pragma unroll
    for (int hp = 0; hp < 2; ++hp) {
      #pragma unroll
      for (int ms = 0; ms < 2; ++ms) {
        const int row = ((role * 2 + hp) * 32 + ms * 16 + l15) * 64;
        kOff[hp][ms][0] = row + (g ^ x7) * 8;
        kOff[hp][ms][1] = row + ((4 + g) ^ x7) * 8;
      }
      const int xv = (l15 >> 1) & 3;
      #pragma unroll
      for (int dsub = 0; dsub < 4; ++dsub)
        vOff[hp][dsub] = ((role * 2 + hp) * 64 + dsub * 16 + l15) * 32 + (g ^ xv) * 8;
    }
  }

  // staging bases (pre-swizzled global sources, linear LDS dst)
  const u16* pK = qkvb + (size_t)(b * 2048 + m0 + (lane >> 3)) * 1536 + 512
                + w * 64 + ((lane & 7) ^ (lane >> 3)) * 8;
  const u16* pV = vt + (size_t)(b * 512 + w * 64 + (lane >> 2)) * 2048 + m0
                + ((lane & 3) ^ ((lane >> 3) & 3)) * 8;

  float pe_f[2][2][2][4];   // [hp][ms][ns][r] e-values
  sv8 pf[2][2];             // P^T A-frags [hp][ns]
  f32x4 acc[2][4][2] = {};
  u32* mySum = sSum + (q2 << 11) + (role << 7) + lane * 2;
  const u32* rdSum = sSum + (q2 << 11) + lane * 2;

  const u16* pKrun = pK;    // running pointers (no per-tile 64b muls)
  const u16* pVrun = pV;

  auto stageK = [&]() {
    #pragma unroll
    for (int i = 0; i < 4; ++i)
      gload_lds16(pKrun + i * 12288, sK + ((w << 2) + i) * 512);
    pKrun += 32 * 1536;
  };
  auto stageV = [&]() {
    #pragma unroll
    for (int i = 0; i < 4; ++i)
      gload_lds16(pVrun + (size_t)i * 32768, sV + ((w << 2) + i) * 512);
    pVrun += 32;
  };
  // QK^T for own 2 heads -> exp2 (Q pre-scaled) -> pe_f + b64 sums -> LDS
  auto qk_step = [&]() {
    #pragma unroll
    for (int hp = 0; hp < 2; ++hp)
      #pragma unroll
      for (int ms = 0; ms < 2; ++ms) {
        sv8 k0 = *(const sv8*)(sK + kOff[hp][ms][0]);
        sv8 k1 = *(const sv8*)(sK + kOff[hp][ms][1]);
        #pragma unroll
        for (int ns = 0; ns < 2; ++ns) {
          f32x4 s = {0.f, 0.f, 0.f, 0.f};
          s = mfma16(k0, Q[hp][ns][0], s);
          s = mfma16(k1, Q[hp][ns][1], s);
          #pragma unroll
          for (int r = 0; r < 4; ++r)
            pe_f[hp][ms][ns][r] = __builtin_amdgcn_exp2f(s[r]);
        }
      }
    #pragma unroll
    for (int ms = 0; ms < 2; ++ms)
      #pragma unroll
      for (int ns = 0; ns < 2; ++ns) {
        const int mn = ms * 2 + ns;
        u32x2 v2;
        v2.x = pkbf(pe_f[0][ms][ns][0] + pe_f[1][ms][ns][0],
                    pe_f[0][ms][ns][1] + pe_f[1][ms][ns][1]);
        v2.y = pkbf(pe_f[0][ms][ns][2] + pe_f[1][ms][ns][2],
                    pe_f[0][ms][ns][3] + pe_f[1][ms][ns][3]);
        *(u32x2*)(mySum + (mn << 9)) = v2;
      }
  };
  // read quad's 4 roles' sums (b64) -> inv; normalize -> pack -> permlane
  auto build_pf = [&]() {
    float inv[2][2][4];
    #pragma unroll
    for (int ms = 0; ms < 2; ++ms)
      #pragma unroll
      for (int ns = 0; ns < 2; ++ns) {
        const int mn = ms * 2 + ns;
        float t0 = 0.f, t1 = 0.f, t2 = 0.f, t3 = 0.f;
        #pragma unroll
        for (int p = 0; p < 4; ++p) {
          u32x2 v = *(const u32x2*)(rdSum + (mn << 9) + (p << 7));
          t0 += __builtin_bit_cast(float, v.x << 16);
          t1 += __builtin_bit_cast(float, v.x & 0xffff0000u);
          t2 += __builtin_bit_cast(float, v.y << 16);
          t3 += __builtin_bit_cast(float, v.y & 0xffff0000u);
        }
        inv[ms][ns][0] = __builtin_amdgcn_rcpf(t0);
        inv[ms][ns][1] = __builtin_amdgcn_rcpf(t1);
        inv[ms][ns][2] = __builtin_amdgcn_rcpf(t2);
        inv[ms][ns][3] = __builtin_amdgcn_rcpf(t3);
      }
    #pragma unroll
    for (int hp = 0; hp < 2; ++hp)
      #pragma unroll
      for (int ns = 0; ns < 2; ++ns) {
        float p[8];
        #pragma unroll
        for (int ms = 0; ms < 2; ++ms)
          #pragma unroll
          for (int r = 0; r < 4; ++r)
            p[ms * 4 + r] = pe_f[hp][ms][ns][r] * inv[ms][ns][r];
        u32 pa = pkbf(p[0], p[1]), pc = pkbf(p[2], p[3]);
        u32 pb_ = pkbf(p[4], p[5]), pd = pkbf(p[6], p[7]);
        asm("v_permlane32_swap_b32 %0, %1" : "+v"(pa), "+v"(pb_));
        asm("v_permlane16_swap_b32 %0, %1" : "+v"(pa), "+v"(pb_));
        asm("v_permlane32_swap_b32 %0, %1" : "+v"(pc), "+v"(pd));
        asm("v_permlane16_swap_b32 %0, %1" : "+v"(pc), "+v"(pd));
        u32x4 pw; pw.x = pa; pw.y = pc; pw.z = pb_; pw.w = pd;
        pf[hp][ns] = __builtin_bit_cast(sv8, pw);
      }
  };
  auto do_pv = [&]() {
    #pragma unroll
    for (int hp = 0; hp < 2; ++hp)
      #pragma unroll
      for (int dsub = 0; dsub < 4; ++dsub) {
        sv8 vf = *(const sv8*)(sV + vOff[hp][dsub]);
        #pragma unroll
        for (int ns = 0; ns < 2; ++ns)
          acc[hp][dsub][ns] = mfma16(pf[hp][ns], vf, acc[hp][dsub][ns]);
      }
  };

  stageK(); stageV();
  __syncthreads();                 // drain stage(0)
  qk_step();                       // tile 0 scores + sums
  for (int t = 0; t < 16; ++t) {
    __syncthreads();               // B2: sums(t) visible, V(t) drained
    if (t < 15) stageK();          // K(t+1), in flight under pf-build + PV
    build_pf();
    do_pv();
    __syncthreads();               // B3: K(t+1) drained, sV/sSum free
    if (t < 15) { stageV(); qk_step(); }  // V(t+1) in flight under next QK
  }
  // ---- store partials (plain bf16, no atomics) ----
  #pragma unroll
  for (int hp = 0; hp < 2; ++hp)
    #pragma unroll
    for (int dsub = 0; dsub < 4; ++dsub)
      #pragma unroll
      for (int ns = 0; ns < 2; ++ns)
        #pragma unroll
        for (int r = 0; r < 4; ++r)
          pbuf[(size_t)(row0 + ns * 16 + g * 4 + r) * 512
               + (role * 2 + hp) * 64 + dsub * 16 + l15] = f2bf(acc[hp][dsub][ns][r]);
}

// ---------------- combine the four m-quarter partials -> bf16 ----------------
__global__ __launch_bounds__(256) void cmb4(
    const u16* __restrict__ a, const u16* __restrict__ b,
    const u16* __restrict__ c, const u16* __restrict__ d,
    u16* __restrict__ o)
{
  const int i = blockIdx.x * 256 + threadIdx.x;  // 262144 total, 8 elems each
  usv8 va = *(const usv8*)(a + (size_t)i * 8);
  usv8 vb = *(const usv8*)(b + (size_t)i * 8);
  usv8 vc = *(const usv8*)(c + (size_t)i * 8);
  usv8 vd = *(const usv8*)(d + (size_t)i * 8);
  usv8 r;
  #pragma unroll
  for (int j = 0; j < 8; ++j)
    r[j] = f2bf((bf2f(va[j]) + bf2f(vb[j])) + (bf2f(vc[j]) + bf2f(vd[j])));
  *(usv8*)(o + (size_t)i * 8) = r;
}

extern "C" void kernel_launch(void* const* d_in, const int* in_sizes, int n_in,
                              void* d_out, int out_size, void* d_ws, size_t ws_size,
                              hipStream_t stream) {
  const float* x      = (const float*)d_in[0];
  const float* ln_g   = (const float*)d_in[1];
  const float* ln_b   = (const float*)d_in[2];
  const float* qkv_w  = (const float*)d_in[3];
  const float* proj_w = (const float*)d_in[4];
  const float* proj_b = (const float*)d_in[5];
  const float* fc1_w  = (const float*)d_in[6];
  const float* fc1_b  = (const float*)d_in[7];
  const float* fc2_w  = (const float*)d_in[8];
  const float* fc2_b  = (const float*)d_in[9];
  char* ws = (char*)d_ws;
  u16*   w_qkv  = (u16*)(ws + 0);         // 1536x512 bf16
  u16*   w_proj = (u16*)(ws + 1572864);   // 512x512
  u16*   w_fc1  = (u16*)(ws + 2097152);   // 2048x512
  u16*   w_fc2  = (u16*)(ws + 4194304);   // 512x2048
  u16*   xn     = (u16*)(ws + 6291456);   // 4096x512 bf16 (LN out; reused as pt0)
  u16*   qkvb   = (u16*)(ws + 10485760);  // 4096x1536 bf16 (V third unused)
  u16*   vtb    = (u16*)(ws + 23068672);  // [2][8][64][2048] bf16
  u16*   attnb  = (u16*)(ws + 35651584);  // 4096x512 bf16
  float* x1     = (float*)(ws + 39845888);// 4096x512 f32
  u16*   hbuf   = (u16*)(ws + 48234496);  // 4096x2048 bf16 (pt1..pt3 pre-fc1)

  u16* pt0 = xn;                 // free after qkv GEMM consumes xn
  u16* pt1 = hbuf;               // hbuf free until fc1
  u16* pt2 = hbuf + 2097152;
  u16* pt3 = hbuf + 4194304;

  prep_kernel<<<4096, 256, 0, stream>>>(qkv_w, proj_w, fc1_w, fc2_w,
                                        w_qkv, w_proj, w_fc1, w_fc2,
                                        x, ln_g, ln_b, xn);
  gemm_kernel<3, 128, 64><<<dim3(32, 24), 256, 0, stream>>>(
      xn, w_qkv, 512, 1536, nullptr, (const float*)vtb, qkvb);
  attn_kernel<<<256, 512, 0, stream>>>(qkvb, vtb, pt0, pt1, pt2, pt3);
  cmb4<<<1024, 256, 0, stream>>>(pt0, pt1, pt2, pt3, attnb);
  gemm_k128<1><<<dim3(64, 8), 256, 0, stream>>>(
      attnb, w_proj, 512, 512, proj_b, x, x1);
  ln_kernel<<<1024, 256, 0, stream>>>(x1, ln_g, ln_b, xn);
  gemm_kernel<2, 128, 128><<<dim3(32, 16), 256, 0, stream>>>(
      xn, w_fc1, 512, 2048, fc1_b, nullptr, hbuf);
  gemm_k128<1><<<dim3(64, 8), 256, 0, stream>>>(
      hbuf, w_fc2, 2048, 512, fc2_b, x1, d_out);
}